// Round 3
// baseline (332.129 us; speedup 1.0000x reference)
//
#include <hip/hip_runtime.h>
#include <hip/hip_bf16.h>

// RGCN CSR, two layers, MI355X.
// h[i] = sum_r (sum_{e in row i, rel=r} x[src_e]) @ W1[r]  -> per-row gather into
// A-row[512] then GEMM with K=512 (bf16 MFMA).
//
// R2 change: FUSED gather+GEMM. Each wave gathers its own 16 rows (one MFMA
// m-tile) into a private 16KB LDS slice (XOR-swizzled vs the stride-1KB
// ds_read_b128 bank conflict), then computes the GEMM itself — no A-buffer
// HBM round trip (saves ~150MB/layer), no __syncthreads (no cross-wave LDS).
// Gather processes rows in pairs with all 32 source loads issued upfront.

typedef __attribute__((ext_vector_type(8))) short short8;
typedef __attribute__((ext_vector_type(4))) float floatx4;

#define DK 512          // R * D = 8 * 64, flattened K dimension
#define ROWS 64         // LDS tile rows per block = 4 waves x 16

static __device__ __forceinline__ unsigned short f2bf(float f) {
    unsigned u = __float_as_uint(f);
    u += 0x7FFFu + ((u >> 16) & 1u);      // RNE
    return (unsigned short)(u >> 16);
}
static __device__ __forceinline__ float bf2f(unsigned short h) {
    return __uint_as_float(((unsigned)h) << 16);
}

// ---- cast x (f32) -> bf16, 4 elems/thread ----
__global__ void k_cast(const float* __restrict__ x, unsigned short* __restrict__ o, int n4) {
    int i = blockIdx.x * blockDim.x + threadIdx.x;
    if (i >= n4) return;
    float4 v = ((const float4*)x)[i];
    ushort4 r;
    r.x = f2bf(v.x); r.y = f2bf(v.y); r.z = f2bf(v.z); r.w = f2bf(v.w);
    ((ushort4*)o)[i] = r;
}

// ---- pack W1[r][d][f] -> BT1[f][r*64+d] (bf16), W2 likewise into BT2[48?][512] ----
__global__ void k_packw(const float* __restrict__ W1, const float* __restrict__ W2,
                        unsigned short* __restrict__ BT1, unsigned short* __restrict__ BT2) {
    int i = blockIdx.x * 256 + threadIdx.x;
    if (i < 64 * 512) {
        int f = i >> 9, rd = i & 511;
        int r = rd >> 6, d = rd & 63;
        BT1[i] = f2bf(W1[(r << 12) + (d << 6) + f]);
    } else if (i < 64 * 512 + 40 * 512) {
        int j = i - 64 * 512;
        int f = j >> 9, rd = j & 511;
        int r = rd >> 6, d = rd & 63;
        BT2[j] = f2bf(W2[r * 2560 + d * 40 + f]);
    }
}

// accumulate one edge value into the 8 per-relation registers (r is an SGPR)
static __device__ __forceinline__ void acc_edge(float* c, int r, float v) {
    if (r == 0) c[0] += v;
    else if (r == 1) c[1] += v;
    else if (r == 2) c[2] += v;
    else if (r == 3) c[3] += v;
    else if (r == 4) c[4] += v;
    else if (r == 5) c[5] += v;
    else if (r == 6) c[6] += v;
    else c[7] += v;
}

// LDS byte layout: row lrow, feature k (bf16) lives at lrow*1024 + ((k*2) ^ ((lrow&7)<<4)).
// XOR on byte bits 4-6 spreads the 8-row stripe across 8 distinct 16B slots so the
// GEMM's 16-lane stride-1KB ds_read_b128 is 2-way (free) instead of 16-way.
static __device__ __forceinline__ void lds_store_row(char* As, int lrow, int lane, const float* c) {
    int swz = (lrow & 7) << 4;
    int base = lrow << 10;
#pragma unroll
    for (int r = 0; r < 8; ++r) {
        int off = base + (((((r << 6) + lane)) << 1) ^ swz);
        *(unsigned short*)(As + off) = f2bf(c[r]);
    }
}

// fast path: two consecutive deg-16 rows; all 32 gather loads issued before accumulation
static __device__ __forceinline__ void gather_pair_fast(
    const unsigned short* __restrict__ src, const int* __restrict__ idxr,
    const int* __restrict__ relr, int lane, float* ca, float* cb) {
    float va[16], vb[16];
#pragma unroll
    for (int t = 0; t < 16; ++t) va[t] = bf2f(src[(size_t)idxr[t] * 64 + lane]);
#pragma unroll
    for (int t = 0; t < 16; ++t) vb[t] = bf2f(src[(size_t)idxr[16 + t] * 64 + lane]);
#pragma unroll
    for (int t = 0; t < 16; ++t) acc_edge(ca, relr[t], va[t]);
#pragma unroll
    for (int t = 0; t < 16; ++t) acc_edge(cb, relr[16 + t], vb[t]);
}

static __device__ __forceinline__ void gather_row_any(
    const unsigned short* __restrict__ src, const int* __restrict__ idx,
    const int* __restrict__ rel, int ps, int deg, int lane, float* c) {
    for (int t = 0; t < deg; ++t) {
        int s = idx[ps + t];
        int r = rel[ps + t];
        acc_edge(c, r, bf2f(src[(size_t)s * 64 + lane]));
    }
}

// gather this wave's 16 rows into its LDS slice
static __device__ __forceinline__ void gather_tile(
    const unsigned short* __restrict__ src, const int* __restrict__ ptr,
    const int* __restrict__ idx, const int* __restrict__ rel,
    char* As, int base /*wave's first global row, uniform*/, int wslot /*wid*16*/,
    int lane, int M) {
#pragma unroll 2
    for (int p = 0; p < 8; ++p) {
        int ra = base + p * 2;
        if (ra + 1 < M) {
            int p0 = ptr[ra], p1 = ptr[ra + 1], p2 = ptr[ra + 2];
            float ca[8] = {0, 0, 0, 0, 0, 0, 0, 0}, cb[8] = {0, 0, 0, 0, 0, 0, 0, 0};
            if (p1 - p0 == 16 && p2 - p1 == 16) {
                gather_pair_fast(src, idx + p0, rel + p0, lane, ca, cb);
            } else {
                gather_row_any(src, idx, rel, p0, p1 - p0, lane, ca);
                gather_row_any(src, idx, rel, p1, p2 - p1, lane, cb);
            }
            lds_store_row(As, wslot + p * 2, lane, ca);
            lds_store_row(As, wslot + p * 2 + 1, lane, cb);
        } else if (ra < M) {
            int p0 = ptr[ra], p1 = ptr[ra + 1];
            float ca[8] = {0, 0, 0, 0, 0, 0, 0, 0};
            gather_row_any(src, idx, rel, p0, p1 - p0, lane, ca);
            lds_store_row(As, wslot + p * 2, lane, ca);
        }
    }
}

// ---- fused layer 1: gather -> GEMM(K=512, N=64) -> relu -> h bf16 ----
__global__ __launch_bounds__(256) void k_fused1(
    const unsigned short* __restrict__ src, const int* __restrict__ ptr,
    const int* __restrict__ idx, const int* __restrict__ rel,
    const unsigned short* __restrict__ BT, unsigned short* __restrict__ H, int M) {
    __shared__ char As[ROWS * 1024];
    int lane = threadIdx.x & 63;
    int wid = __builtin_amdgcn_readfirstlane(threadIdx.x >> 6);
    int base = blockIdx.x * ROWS + wid * 16;

    gather_tile(src, ptr, idx, rel, As, base, wid * 16, lane, M);

    int lr = lane & 15, lg = lane >> 4;
    int lrow = wid * 16 + lr;
    int swz = (lrow & 7) << 4;
    const char* Ab = As + (lrow << 10);
    const unsigned short* Bb = BT + (size_t)lr * DK + lg * 8;
    floatx4 acc[4] = {};
#pragma unroll 4
    for (int k0 = 0; k0 < DK; k0 += 32) {
        short8 a = *(const short8*)(Ab + ((((k0 + lg * 8) << 1)) ^ swz));
        short8 b0 = *(const short8*)(Bb + k0);
        short8 b1 = *(const short8*)(Bb + 16 * DK + k0);
        short8 b2 = *(const short8*)(Bb + 32 * DK + k0);
        short8 b3 = *(const short8*)(Bb + 48 * DK + k0);
        acc[0] = __builtin_amdgcn_mfma_f32_16x16x32_bf16(a, b0, acc[0], 0, 0, 0);
        acc[1] = __builtin_amdgcn_mfma_f32_16x16x32_bf16(a, b1, acc[1], 0, 0, 0);
        acc[2] = __builtin_amdgcn_mfma_f32_16x16x32_bf16(a, b2, acc[2], 0, 0, 0);
        acc[3] = __builtin_amdgcn_mfma_f32_16x16x32_bf16(a, b3, acc[3], 0, 0, 0);
    }
    // C/D layout: col = lane&15, row = (lane>>4)*4 + reg
#pragma unroll
    for (int nt = 0; nt < 4; ++nt)
#pragma unroll
        for (int i = 0; i < 4; ++i) {
            int row = base + lg * 4 + i;
            if (row < M)
                H[(size_t)row * 64 + nt * 16 + lr] = f2bf(fmaxf(acc[nt][i], 0.0f));
        }
}

// ---- fused layer 2: gather(h) -> GEMM(K=512, N=48 incl 8 pad) -> log_softmax -> f32 ----
__global__ __launch_bounds__(256) void k_fused2(
    const unsigned short* __restrict__ src, const int* __restrict__ ptr,
    const int* __restrict__ idx, const int* __restrict__ rel,
    const unsigned short* __restrict__ BT, float* __restrict__ out, int M) {
    __shared__ char As[ROWS * 1024];
    int lane = threadIdx.x & 63;
    int wid = __builtin_amdgcn_readfirstlane(threadIdx.x >> 6);
    int base = blockIdx.x * ROWS + wid * 16;

    gather_tile(src, ptr, idx, rel, As, base, wid * 16, lane, M);

    int lr = lane & 15, lg = lane >> 4;
    int lrow = wid * 16 + lr;
    int swz = (lrow & 7) << 4;
    const char* Ab = As + (lrow << 10);
    const unsigned short* Bb = BT + (size_t)lr * DK + lg * 8;
    floatx4 acc[3] = {};
#pragma unroll 4
    for (int k0 = 0; k0 < DK; k0 += 32) {
        short8 a = *(const short8*)(Ab + ((((k0 + lg * 8) << 1)) ^ swz));
        short8 b0 = *(const short8*)(Bb + k0);
        short8 b1 = *(const short8*)(Bb + 16 * DK + k0);
        short8 b2 = *(const short8*)(Bb + 32 * DK + k0);   // cols 32..47; 40..47 pad, masked below
        acc[0] = __builtin_amdgcn_mfma_f32_16x16x32_bf16(a, b0, acc[0], 0, 0, 0);
        acc[1] = __builtin_amdgcn_mfma_f32_16x16x32_bf16(a, b1, acc[1], 0, 0, 0);
        acc[2] = __builtin_amdgcn_mfma_f32_16x16x32_bf16(a, b2, acc[2], 0, 0, 0);
    }
    bool c2ok = lr < 8;   // n-frag 2 covers cols 32..47; valid iff col < 40
#pragma unroll
    for (int i = 0; i < 4; ++i) {
        float v0 = acc[0][i], v1 = acc[1][i], v2 = acc[2][i];
        float mx = fmaxf(v0, v1);
        if (c2ok) mx = fmaxf(mx, v2);
#pragma unroll
        for (int off = 1; off < 16; off <<= 1)
            mx = fmaxf(mx, __shfl_xor(mx, off, 16));
        float s = __expf(v0 - mx) + __expf(v1 - mx) + (c2ok ? __expf(v2 - mx) : 0.0f);
#pragma unroll
        for (int off = 1; off < 16; off <<= 1)
            s += __shfl_xor(s, off, 16);
        float lse = mx + __logf(s);
        int row = base + lg * 4 + i;
        if (row < M) {
            float* orow = out + (size_t)row * 40;
            orow[lr] = v0 - lse;
            orow[16 + lr] = v1 - lse;
            if (c2ok) orow[32 + lr] = v2 - lse;
        }
    }
}

extern "C" void kernel_launch(void* const* d_in, const int* in_sizes, int n_in,
                              void* d_out, int out_size, void* d_ws, size_t ws_size,
                              hipStream_t stream) {
    const float* x  = (const float*)d_in[0];
    const int* ptr  = (const int*)d_in[1];
    const int* idx  = (const int*)d_in[2];
    const int* rel  = (const int*)d_in[3];
    const float* W1 = (const float*)d_in[4];
    const float* W2 = (const float*)d_in[5];
    float* out = (float*)d_out;

    int N = in_sizes[1] - 1;                 // 75000
    int nblk = (N + ROWS - 1) / ROWS;        // 1172
    int MP = nblk * ROWS;                    // 75008

    char* ws = (char*)d_ws;
    size_t szRow64 = (size_t)MP * 64 * 2;    // bf16 [MP,64]
    unsigned short* xbf = (unsigned short*)(ws);
    unsigned short* hbf = (unsigned short*)(ws + szRow64);
    unsigned short* BT1 = (unsigned short*)(ws + 2 * szRow64);
    unsigned short* BT2 = (unsigned short*)(ws + 2 * szRow64 + 64 * 512 * 2);
    // ws use: 2*9.6MB + 64KB + 48KB ~= 19.3MB

    int n4 = N * 16;                          // N*64/4 f32 quads
    k_cast<<<(n4 + 255) / 256, 256, 0, stream>>>(x, xbf, n4);
    k_packw<<<(64 * 512 + 40 * 512 + 255) / 256, 256, 0, stream>>>(W1, W2, BT1, BT2);

    k_fused1<<<nblk, 256, 0, stream>>>(xbf, ptr, idx, rel, BT1, hbf, N);
    k_fused2<<<nblk, 256, 0, stream>>>(hbf, ptr, idx, rel, BT2, out, N);
}

// Round 4
// 129.766 us; speedup vs baseline: 2.5594x; 2.5594x over previous
//
#include <hip/hip_runtime.h>
#include <hip/hip_bf16.h>

// RGCN CSR, two layers, MI355X.  R3: transform-then-gather.
//   xw1[(n*8+r)*64 + f] = (x @ W1[r])[n,f]   (dense GEMM, K=64, bf16 MFMA)
//   h[n,f] = relu( sum_{e in row n} xw1[(idx_e*8+rel_e)*64 + f] )   (branch-free gather)
//   xw2[(n*8+r)*40 + f] = (h @ W2[r])[n,f]
//   out = log_softmax( sum_e xw2[...] )
// Gather per edge = ONE load at a wave-uniform base (scalar idx/rel) + add:
// no relation dispatch (R2's VALU hog), 16 independent loads in flight,
// tiny kernels -> high occupancy (the R2 fusion died at 19% occupancy).

typedef __attribute__((ext_vector_type(8))) short short8;
typedef __attribute__((ext_vector_type(4))) float floatx4;

static __device__ __forceinline__ unsigned short f2bf(float f) {
    unsigned u = __float_as_uint(f);
    u += 0x7FFFu + ((u >> 16) & 1u);      // RNE
    return (unsigned short)(u >> 16);
}
static __device__ __forceinline__ float bf2f(unsigned short h) {
    return __uint_as_float(((unsigned)h) << 16);
}

// ---- cast x (f32) -> bf16 [MP rows], zero the pad rows ----
__global__ void k_cast(const float* __restrict__ x, unsigned short* __restrict__ o,
                       int n4, int np4) {
    int i = blockIdx.x * blockDim.x + threadIdx.x;
    if (i >= np4) return;
    ushort4 r;
    if (i < n4) {
        float4 v = ((const float4*)x)[i];
        r.x = f2bf(v.x); r.y = f2bf(v.y); r.z = f2bf(v.z); r.w = f2bf(v.w);
    } else {
        r.x = r.y = r.z = r.w = 0;
    }
    ((ushort4*)o)[i] = r;
}

// ---- pack weights as B^T with K = input-feature dim ----
// BT1[j][d] = W1[r][d][f], j = r*64+f   (512 x 64)
// BT2[j][d] = W2[r][d][f], j = r*40+f   (320 x 64)
__global__ void k_packw(const float* __restrict__ W1, const float* __restrict__ W2,
                        unsigned short* __restrict__ BT1, unsigned short* __restrict__ BT2) {
    int i = blockIdx.x * 256 + threadIdx.x;
    if (i < 512 * 64) {
        int j = i >> 6, d = i & 63;
        int r = j >> 6, f = j & 63;
        BT1[i] = f2bf(W1[r * 4096 + d * 64 + f]);
    } else if (i < 512 * 64 + 320 * 64) {
        int ii = i - 512 * 64;
        int j = ii >> 6, d = ii & 63;
        int r = j / 40, f = j - r * 40;
        BT2[ii] = f2bf(W2[r * 2560 + d * 40 + f]);
    }
}

// ---- dense GEMM: xw[MP][NC] = A[MP][64] @ BT[NC][64]^T  (K=64, bf16 MFMA) ----
// Block 256 thr = 4 waves; wave = 64 rows x 64 cols (4x4 frags); block = 256 rows.
__global__ __launch_bounds__(256) void k_xw(
    const unsigned short* __restrict__ A, const unsigned short* __restrict__ BT,
    unsigned short* __restrict__ xw, int NC, int nColBlk) {
    int bid = blockIdx.x;
    int cb = bid % nColBlk, rb = bid / nColBlk;
    int wave = threadIdx.x >> 6, lane = threadIdx.x & 63;
    int lr = lane & 15, lg = lane >> 4;
    int rowbase = rb * 256 + wave * 64;
    int col0 = cb * 64;
    floatx4 acc[4][4] = {};
#pragma unroll
    for (int k0 = 0; k0 < 2; ++k0) {
        int koff = k0 * 32 + lg * 8;
        short8 a[4], b[4];
#pragma unroll
        for (int mt = 0; mt < 4; ++mt)
            a[mt] = *(const short8*)(A + (size_t)(rowbase + mt * 16 + lr) * 64 + koff);
#pragma unroll
        for (int nt = 0; nt < 4; ++nt)
            b[nt] = *(const short8*)(BT + (size_t)(col0 + nt * 16 + lr) * 64 + koff);
#pragma unroll
        for (int mt = 0; mt < 4; ++mt)
#pragma unroll
            for (int nt = 0; nt < 4; ++nt)
                acc[mt][nt] = __builtin_amdgcn_mfma_f32_16x16x32_bf16(a[mt], b[nt], acc[mt][nt], 0, 0, 0);
    }
    // C/D layout: col = lane&15, row = (lane>>4)*4 + i
#pragma unroll
    for (int mt = 0; mt < 4; ++mt)
#pragma unroll
        for (int nt = 0; nt < 4; ++nt)
#pragma unroll
            for (int i = 0; i < 4; ++i) {
                int row = rowbase + mt * 16 + lg * 4 + i;   // always < MP
                xw[(size_t)row * NC + col0 + nt * 16 + lr] = f2bf(acc[mt][nt][i]);
            }
}

// ---- gather-sum + relu -> h bf16 [MP][64]; zero pad rows ----
__global__ __launch_bounds__(256) void k_gs_relu(
    const unsigned short* __restrict__ xw,   // viewed as [(n*8+r)][64]
    const int* __restrict__ ptr, const int* __restrict__ idx,
    const int* __restrict__ rel,
    unsigned short* __restrict__ H, int M, int MP) {
    int row = blockIdx.x * 4 + (threadIdx.x >> 6);
    int lane = threadIdx.x & 63;
    if (row >= MP) return;
    row = __builtin_amdgcn_readfirstlane(row);
    if (row >= M) { H[(size_t)row * 64 + lane] = 0; return; }
    int ps = ptr[row], pe = ptr[row + 1];
    int deg = pe - ps;
    const int* __restrict__ idxr = idx + ps;
    const int* __restrict__ relr = rel + ps;
    float c = 0.f;
    if (deg == 16) {
        float v[16];
#pragma unroll
        for (int t = 0; t < 16; ++t) {
            size_t o = ((size_t)idxr[t] * 8 + relr[t]) * 64;   // scalar base
            v[t] = bf2f(xw[o + lane]);                          // independent loads
        }
#pragma unroll
        for (int t = 0; t < 16; ++t) c += v[t];
    } else {
        for (int t = 0; t < deg; ++t) {
            size_t o = ((size_t)idxr[t] * 8 + relr[t]) * 64;
            c += bf2f(xw[o + lane]);
        }
    }
    H[(size_t)row * 64 + lane] = f2bf(fmaxf(c, 0.f));
}

// ---- gather-sum + log_softmax -> out f32 [M][40] ----
__global__ __launch_bounds__(256) void k_gs_lsm(
    const unsigned short* __restrict__ xw,   // viewed as [(n*8+r)][40]
    const int* __restrict__ ptr, const int* __restrict__ idx,
    const int* __restrict__ rel,
    float* __restrict__ out, int M) {
    int row = blockIdx.x * 4 + (threadIdx.x >> 6);
    int lane = threadIdx.x & 63;
    if (row >= M) return;
    row = __builtin_amdgcn_readfirstlane(row);
    int ps = ptr[row], pe = ptr[row + 1];
    int deg = pe - ps;
    const int* __restrict__ idxr = idx + ps;
    const int* __restrict__ relr = rel + ps;
    bool ok = lane < 40;
    int l = ok ? lane : 0;
    float c = 0.f;
    if (deg == 16) {
        float v[16];
#pragma unroll
        for (int t = 0; t < 16; ++t) {
            size_t o = ((size_t)idxr[t] * 8 + relr[t]) * 40;
            v[t] = bf2f(xw[o + l]);
        }
#pragma unroll
        for (int t = 0; t < 16; ++t) c += v[t];
    } else {
        for (int t = 0; t < deg; ++t) {
            size_t o = ((size_t)idxr[t] * 8 + relr[t]) * 40;
            c += bf2f(xw[o + l]);
        }
    }
    // log-softmax across lanes 0..39 (full-wave butterfly, neutral fill)
    float mx = ok ? c : -INFINITY;
#pragma unroll
    for (int m = 1; m < 64; m <<= 1) mx = fmaxf(mx, __shfl_xor(mx, m, 64));
    float e = ok ? __expf(c - mx) : 0.f;
    float s = e;
#pragma unroll
    for (int m = 1; m < 64; m <<= 1) s += __shfl_xor(s, m, 64);
    if (ok) out[(size_t)row * 40 + lane] = c - mx - __logf(s);
}

extern "C" void kernel_launch(void* const* d_in, const int* in_sizes, int n_in,
                              void* d_out, int out_size, void* d_ws, size_t ws_size,
                              hipStream_t stream) {
    const float* x  = (const float*)d_in[0];
    const int* ptr  = (const int*)d_in[1];
    const int* idx  = (const int*)d_in[2];
    const int* rel  = (const int*)d_in[3];
    const float* W1 = (const float*)d_in[4];
    const float* W2 = (const float*)d_in[5];
    float* out = (float*)d_out;

    int N = in_sizes[1] - 1;                 // 75000
    int MP = (N + 255) & ~255;               // 75008 (multiple of 256)

    char* ws = (char*)d_ws;
    size_t szRow64 = (size_t)MP * 64 * 2;    // 9.6MB
    unsigned short* xbf  = (unsigned short*)(ws);
    unsigned short* hbf  = (unsigned short*)(ws + szRow64);
    unsigned short* BT1  = (unsigned short*)(ws + 2 * szRow64);
    unsigned short* BT2  = (unsigned short*)(ws + 2 * szRow64 + 512 * 64 * 2);
    unsigned short* xwb  = (unsigned short*)(ws + 2 * szRow64 + 512 * 64 * 2 + 320 * 64 * 2);
    // xw1 [MP][512] = 76.8MB; xw2 [MP][320] aliases the same region (xw1 dead
    // after k_gs_relu).  Total ws use ~= 96.2MB (same footprint as R1, fits).

    int n4 = N * 16, np4 = MP * 16;
    k_cast<<<(np4 + 255) / 256, 256, 0, stream>>>(x, xbf, n4, np4);
    k_packw<<<(512 * 64 + 320 * 64 + 255) / 256, 256, 0, stream>>>(W1, W2, BT1, BT2);

    int nrb = MP / 256;                      // 293
    // layer 1: xw1 = x @ W1 (NC=512, 8 col-blocks)
    k_xw<<<nrb * 8, 256, 0, stream>>>(xbf, BT1, xwb, 512, 8);
    k_gs_relu<<<MP / 4, 256, 0, stream>>>(xwb, ptr, idx, rel, hbf, N, MP);
    // layer 2: xw2 = h @ W2 (NC=320, 5 col-blocks), aliases xwb
    k_xw<<<nrb * 5, 256, 0, stream>>>(hbf, BT2, xwb, 320, 5);
    k_gs_lsm<<<(N + 3) / 4, 256, 0, stream>>>(xwb, ptr, idx, rel, out, N);
}